// Round 5
// baseline (257.512 us; speedup 1.0000x reference)
//
#include <hip/hip_runtime.h>
#include <math.h>
#include <stdint.h>

// VectorQuantizer forward on MI355X — round 9.
//
// Numerics (verified R1-R8, absmax <=9.8e-4 = perplexity float rounding):
//  * probs == one_hot(argmax)           -> z_q[n] = emb[idx[n]]
//  * argmax_j softmax((-d+g)/TAU) == argmax_j ( g[n,j] - ||e_j||^2 + 2 z_n.e_j )
//  * LAMB*ortho ~1.5e-9 sub-ULP of loss -> skipped (exact no-op in fp32)
//  * loss = mse*(1+BETA^2);  fp16 split z.e = zh.eh + (zh.el' + zl'.eh)*2^-11
//
// R9 (pipeline the K-loop; reverts of measured-neutral R8 pieces):
//  * R8 post-mortem: old loop was {barrier; compute; barrier; STAGE(k+1)} —
//    stage issued right BEFORE the next vmcnt(0) drain => full global->LDS
//    latency exposed every K-step. Fix: BK=32 double-buffered staging
//    (2x24KB), T3 minimum-2-phase order {STAGE(k+1); compute(k); barrier}:
//    stage latency hides under ~1150cy of ds_read/MFMA.
//  * Staging swizzle re-derived for 4 chunks/row: c=(s&3)^((row>>1)&3)
//    spans all 8 bank-quads over 8 consecutive rows (same conflict profile
//    as the verified BK=64 (s&7)^(row&7) layout).
//  * u: revert R8's LDS staging (measured neutral, cost occupancy). Back to
//    32 scalar loads, but issued in iter0 + asm-pinned after iter0's compute
//    (rule #17) so the wait hides under iters 1-7, not the epilogue.
//  * KEEP XCD-partitioned swizzle (FETCH 60->45MB measured; L2/L3 win).
//  * outfin: 256 -> 2048 blocks (8 rows each); 17MB of stores at full
//    occupancy instead of 1 block/CU.

#define NROWS 16384
#define NE    1024
#define ED    256
#define EPSF  1e-10f
#define INV2048 4.8828125e-4f
#define BM 128
#define BN 64
#define SCW 68    // score-tile stride: b128 scan ~4-way (1.58x) not 32-way

typedef _Float16 half_t;
typedef __attribute__((ext_vector_type(4))) _Float16 half4;
typedef __attribute__((ext_vector_type(8))) _Float16 half8;
typedef __attribute__((ext_vector_type(16))) float floatx16;
typedef unsigned long long u64;

__device__ __forceinline__ void gl_lds16(const void* g, void* l) {
    __builtin_amdgcn_global_load_lds(
        (const __attribute__((address_space(1))) uint32_t*)g,
        (__attribute__((address_space(3))) uint32_t*)l, 16, 0, 0);
}

// pack (value, code) into an orderable u64; ties -> smaller code (np.argmax)
__device__ __forceinline__ u64 packMax(float v, int code) {
    unsigned int b   = __float_as_uint(v);
    unsigned int key = (b & 0x80000000u) ? ~b : (b | 0x80000000u);
    return ((u64)key << 32) | (unsigned int)(NE - 1 - code);
}

// ---------------- prep: fp16-split z/emb, e-norms, z-norms, zero accumulators
__global__ __launch_bounds__(256) void vq_prep(
        const float* __restrict__ z, const float* __restrict__ emb,
        half_t* __restrict__ zh, half_t* __restrict__ zl,
        half_t* __restrict__ eh, half_t* __restrict__ el,
        float* __restrict__ enorm, float* __restrict__ znorm,
        u64* __restrict__ best, int* __restrict__ cnt,
        double* __restrict__ mse_acc, int* __restrict__ done_cnt)
{
    const int gid = blockIdx.x * 256 + threadIdx.x;
    const int ZQ4 = NROWS * ED / 4;                  // 1048576 = 4096 full blocks
    if (gid < ZQ4) {
        const float4 v = ((const float4*)z)[gid];
        const float x[4] = {v.x, v.y, v.z, v.w};
        half4 h, l;
#pragma unroll
        for (int i = 0; i < 4; ++i) {
            const half_t hi = (half_t)x[i];
            h[i] = hi; l[i] = (half_t)((x[i] - (float)hi) * 2048.0f);
        }
        *(half4*)&zh[(size_t)gid * 4] = h;
        *(half4*)&zl[(size_t)gid * 4] = l;
        float s = v.x*v.x + v.y*v.y + v.z*v.z + v.w*v.w;
#pragma unroll
        for (int o = 32; o; o >>= 1) s += __shfl_down(s, o);
        if ((threadIdx.x & 63) == 0) znorm[gid >> 6] = s;   // 64 thr = 1 row
    } else {
        const int eg = gid - ZQ4;                    // 0..65535
        const float4 v = ((const float4*)emb)[eg];
        const float x[4] = {v.x, v.y, v.z, v.w};
        half4 h, l;
#pragma unroll
        for (int i = 0; i < 4; ++i) {
            const half_t hi = (half_t)x[i];
            h[i] = hi; l[i] = (half_t)((x[i] - (float)hi) * 2048.0f);
        }
        *(half4*)&eh[(size_t)eg * 4] = h;
        *(half4*)&el[(size_t)eg * 4] = l;
        float s = v.x*v.x + v.y*v.y + v.z*v.z + v.w*v.w;
#pragma unroll
        for (int o = 32; o; o >>= 1) s += __shfl_down(s, o);
        if ((threadIdx.x & 63) == 0) enorm[eg >> 6] = s;
        if (eg < NROWS) best[eg] = 0ull;
        if (eg < NE)    cnt[eg]  = 0;
        if (eg == 0)  { *mse_acc = 0.0; *done_cnt = 0; }
    }
}

// ---------------- MFMA GEMM + gumbel + per-row argmax
// 1D grid 2048 blocks, XCD-partitioned (keep: FETCH 60->45MB measured).
// 256 thr, 128x64 tile, 4 waves 2m x 2n, wave = 2x1 of 32x32x16 f16 MFMA
// x {hi.hi, hi.lo, lo.hi}. BK=32, double-buffered staging, 1 barrier/K-step.
__global__ __launch_bounds__(256, 2) void vq_gemm(
        const half_t* __restrict__ zh, const half_t* __restrict__ zl,
        const half_t* __restrict__ eh, const half_t* __restrict__ el,
        const float* __restrict__ u, const float* __restrict__ enorm,
        u64* __restrict__ best)
{
    // per buffer (halves): Ah 4096 | Al 4096 | Bh 2048 | Bl 2048  = 24KB
    __shared__ __align__(16) char smem[49152];
    half_t* SM = (half_t*)smem;
    float (*Sc)[SCW] = (float(*)[SCW])smem;        // 34816B, overlays buffers
    u64* parr = (u64*)(smem + 34816);              // 2048B, still within buf0/1

    const int t    = threadIdx.x;
    const int w    = t >> 6;
    const int lane = t & 63;
    const int lrow = lane & 31;
    const int hw   = lane >> 5;

    const int bid = blockIdx.x;
    const int xcd = bid & 7, c = bid >> 3;
    const int m0 = (xcd * 16 + (c >> 4)) * BM;     // XCD-private m-range
    const int n0 = (c & 15) * BN;
    const int wm = (w >> 1) * 64, wn = (w & 1) * 32;

    // staging descriptors (k-tile-invariant). LDS slot s (16B) holds
    // (row = s>>2, chunk = (s&3)^((row>>1)&3)); pre-swizzled global source,
    // linear LDS dest. 8-quad spread: byte%128 = 64*(row&1)+16*chunk.
    size_t gaoff[2]; size_t gboff;
#pragma unroll
    for (int it = 0; it < 2; ++it) {
        const int s = it * 256 + t;
        const int row = s >> 2;                    // 0..127
        const int cc = (s & 3) ^ ((row >> 1) & 3);
        gaoff[it] = (size_t)(m0 + row) * ED + cc * 8;
    }
    {
        const int row = t >> 2;                    // 0..63
        const int cc = (t & 3) ^ ((row >> 1) & 3);
        gboff = (size_t)(n0 + row) * ED + cc * 8;
    }

    auto STAGE = [&](int kt, int b) {              // k-tile kt -> buffer b
        half_t* base = SM + b * 12288;
        const int kh = kt * 32;
#pragma unroll
        for (int it = 0; it < 2; ++it) {
            const int ldso = (it * 256 + w * 64) * 8;   // wave-uniform base
            gl_lds16(zh + gaoff[it] + kh, base + ldso);
            gl_lds16(zl + gaoff[it] + kh, base + 4096 + ldso);
        }
        gl_lds16(eh + gboff + kh, base + 8192  + w * 64 * 8);
        gl_lds16(el + gboff + kh, base + 10240 + w * 64 * 8);
    };

    floatx16 accH[2] = {};
    floatx16 accX[2] = {};
    const int   col0 = n0 + wn + lrow;
    const float en0  = enorm[col0];
    float ur[2][16];

    STAGE(0, 0);
    __syncthreads();                               // drain stage(0) (one-time)

#pragma unroll
    for (int kt = 0; kt < 8; ++kt) {
        const int cb = kt & 1;
        if (kt + 1 < 8) STAGE(kt + 1, cb ^ 1);     // issue-early: hides under compute
        if (kt == 0) {                             // issue u loads; wait pinned later
            const float* ub = u + (size_t)(m0 + wm + (hw << 2)) * NE + col0;
#pragma unroll
            for (int i = 0; i < 2; ++i)
#pragma unroll
                for (int r = 0; r < 16; ++r)
                    ur[i][r] = ub[(size_t)(i * 32 + (r & 3) + ((r >> 2) << 3)) * NE];
        }
        {   // compute buffer cb
            half_t* base = SM + cb * 12288;
#pragma unroll
            for (int ks = 0; ks < 2; ++ks) {
                const int cch = ks * 2 + hw;       // 16B k-chunk index 0..3
                const int br = wn + lrow;
                const int sb = br * 4 + (cch ^ ((br >> 1) & 3));
                const half8 bh = *(const half8*)&base[8192  + sb * 8];
                const half8 bl = *(const half8*)&base[10240 + sb * 8];
                half8 ah[2], al[2];
#pragma unroll
                for (int i = 0; i < 2; ++i) {
                    const int ar = wm + i * 32 + lrow;
                    const int sa = ar * 4 + (cch ^ ((ar >> 1) & 3));
                    ah[i] = *(const half8*)&base[sa * 8];
                    al[i] = *(const half8*)&base[4096 + sa * 8];
                }
#pragma unroll
                for (int i = 0; i < 2; ++i) {
                    accH[i] = __builtin_amdgcn_mfma_f32_32x32x16_f16(ah[i], bh, accH[i], 0, 0, 0);
                    accX[i] = __builtin_amdgcn_mfma_f32_32x32x16_f16(ah[i], bl, accX[i], 0, 0, 0);
                    accX[i] = __builtin_amdgcn_mfma_f32_32x32x16_f16(al[i], bh, accX[i], 0, 0, 0);
                }
            }
        }
        if (kt == 0) {                             // pin ur live here (rule #17):
#pragma unroll                                     // wait hides under iters 1-7
            for (int i = 0; i < 2; ++i)
#pragma unroll
                for (int r = 0; r < 16; ++r)
                    asm volatile("" :: "v"(ur[i][r]));
        }
        __syncthreads();                           // drains stage(kt+1); buf flip safe
    }
    // loop ends with barrier: all LDS reads done -> Sc overlay safe

    // phase 1: scores (incl. gumbel from pinned regs) -> Sc[row][localcol]
    // C/D layout: col=lane&31, row=(r&3)+8*(r>>2)+4*hw
#pragma unroll
    for (int i = 0; i < 2; ++i) {
#pragma unroll
        for (int r = 0; r < 16; ++r) {
            const int lr = wm + i * 32 + (r & 3) + ((r >> 2) << 3) + (hw << 2);
            const float d = accH[i][r] + accX[i][r] * INV2048;
            const float g = -__logf(-__logf(ur[i][r] + EPSF) + EPSF);
            Sc[lr][wn + lrow] = 2.f * d - en0 + g;
        }
    }
    __syncthreads();

    // phase 2: 2 threads/row scan 32 cols each in registers (ascending cols,
    // strict > keeps first-max = np.argmax tie rule via packMax)
    {
        const int row = t >> 1;
        const int ch  = (t & 1) << 5;
        float bv = -1e38f; int bc = 0;
#pragma unroll
        for (int q = 0; q < 8; ++q) {
            const float4 v = *(const float4*)&Sc[row][ch + (q << 2)];
            const int cc = n0 + ch + (q << 2);
            if (v.x > bv) { bv = v.x; bc = cc; }
            if (v.y > bv) { bv = v.y; bc = cc + 1; }
            if (v.z > bv) { bv = v.z; bc = cc + 2; }
            if (v.w > bv) { bv = v.w; bc = cc + 3; }
        }
        parr[t] = packMax(bv, bc);
    }
    __syncthreads();
    if (t < 128) {
        const u64 a = parr[t << 1], b = parr[(t << 1) + 1];
        atomicMax(&best[m0 + t], a > b ? a : b);
    }
}

// ---------------- broadcast emb[idx] as z_q_st, mse from packed score,
// histogram; last block: final loss + perplexity. No z read at all.
// 2048 blocks x 8 rows: stores run at full occupancy.
__global__ __launch_bounds__(256) void vq_outfin(
        const float* __restrict__ emb, const float* __restrict__ u,
        const u64* __restrict__ best, const float* __restrict__ znorm,
        int* __restrict__ cnt, double* __restrict__ mse_acc,
        int* __restrict__ done_cnt, float* __restrict__ out)
{
    __shared__ int    ridx[8];
    __shared__ double redd[4];
    __shared__ int    flag;
    const int t  = threadIdx.x;
    const int m0 = blockIdx.x * 8;

    if (t < 8) {
        const u64 p = best[m0 + t];                    // written pre-launch
        const unsigned int key = (unsigned int)(p >> 32);
        const int code = NE - 1 - (int)(p & 0xFFFFFFFFu);
        ridx[t] = code;
        atomicAdd(&cnt[code], 1);
        // invert packMax key -> winning score s = 2 z.e - ||e||^2 + g (bit-exact)
        const unsigned int b = (key & 0x80000000u) ? (key ^ 0x80000000u) : ~key;
        const float s  = __uint_as_float(b);
        const float uv = u[(size_t)(m0 + t) * NE + code];
        const float g  = -__logf(-__logf(uv + EPSF) + EPSF);
        // mse_row = ||z||^2 + ||e||^2 - 2 z.e = znorm - s + g
        float lm = znorm[m0 + t] - s + g;
        lm += __shfl_down(lm, 4);
        lm += __shfl_down(lm, 2);
        lm += __shfl_down(lm, 1);
        if (t == 0) atomicAdd(mse_acc, (double)lm);
    }
    __syncthreads();

    // z_q_st == emb[idx] to <=4e-7 of ref's z + (z_q - z). 1KB coalesced
    // store per row; emb row is L2/L3-hot (1MB table).
#pragma unroll
    for (int rr = 0; rr < 8; ++rr) {
        const int j = ridx[rr];
        out[1 + (size_t)(m0 + rr) * ED + t] = emb[(size_t)j * ED + t];
    }

    if (t == 0) {
        __threadfence();
        flag = (atomicAdd(done_cnt, 1) == NROWS / 8 - 1) ? 1 : 0;
    }
    __syncthreads();
    if (flag) {
        // final: loss + perplexity (device-coherent reads via atomic rmw)
        double s = 0.0;
#pragma unroll
        for (int q = 0; q < 4; ++q) {
            const int   cc = atomicAdd(&cnt[(q << 8) + t], 0);
            const float em = (float)cc / (float)NROWS;
            s += (double)(em * logf(em + EPSF));
        }
#pragma unroll
        for (int o = 32; o; o >>= 1) s += __shfl_down(s, o);
        if ((t & 63) == 0) redd[t >> 6] = s;
        __syncthreads();
        if (t == 0) {
            const double tot = redd[0] + redd[1] + redd[2] + redd[3];
            const double mse = atomicAdd(mse_acc, 0.0) / (double)((size_t)NROWS * ED);
            out[0] = (float)(mse * 1.0625);   // mse*(1+BETA^2); ortho sub-ULP
            out[1 + (size_t)NROWS * ED] = (float)exp(-tot);
        }
    }
}

extern "C" void kernel_launch(void* const* d_in, const int* in_sizes, int n_in,
                              void* d_out, int out_size, void* d_ws, size_t ws_size,
                              hipStream_t stream) {
    const float* z   = (const float*)d_in[0];
    const float* emb = (const float*)d_in[1];
    const float* u   = (const float*)d_in[2];
    float* out = (float*)d_out;

    double* mse_acc  = (double*)d_ws;
    int*    done_cnt = (int*)((char*)d_ws + 64);
    int*    cnt      = (int*)((char*)d_ws + 1024);
    float*  enorm    = (float*)((char*)d_ws + 5120);
    u64*    best     = (u64*)((char*)d_ws + 9216);    // 128KB -> ends 140288
    float*  znorm    = (float*)((char*)d_ws + 140288); // 64KB -> ends 205824
    const size_t small_end = 205824;                   // 256-aligned

    const size_t zsplit = (size_t)NROWS * ED * 2;      // 8 MB each
    const size_t esplit = (size_t)NE * ED * 2;         // 0.5 MB each
    const bool bigws = ws_size >= small_end + 2 * zsplit + 2 * esplit;

    half_t *zh, *zl, *eh, *el;
    if (bigws) {
        char* big = (char*)d_ws + small_end;
        zh = (half_t*)big;
        zl = (half_t*)(big + zsplit);
        eh = (half_t*)(big + 2 * zsplit);
        el = (half_t*)(big + 2 * zsplit + esplit);
    } else {
        // stash zh/zl in d_out's z_q_st region (fully consumed by vq_gemm
        // before vq_outfin overwrites it); eh/el in small ws region.
        zh = (half_t*)((char*)d_out + 8);
        zl = (half_t*)((char*)d_out + 8 + zsplit);
        eh = (half_t*)((char*)d_ws + small_end);
        el = (half_t*)((char*)d_ws + small_end + esplit);
    }

    vq_prep<<<(NROWS * ED / 4 + NE * ED / 4) / 256, 256, 0, stream>>>(
        z, emb, zh, zl, eh, el, enorm, znorm, best, cnt, mse_acc, done_cnt);
    vq_gemm<<<(NROWS / BM) * (NE / BN), 256, 0, stream>>>(
        zh, zl, eh, el, u, enorm, best);
    vq_outfin<<<NROWS / 8, 256, 0, stream>>>(
        emb, u, best, znorm, cnt, mse_acc, done_cnt, out);
}

// Round 7
// 186.442 us; speedup vs baseline: 1.3812x; 1.3812x over previous
//
#include <hip/hip_runtime.h>
#include <math.h>
#include <stdint.h>

// VectorQuantizer forward on MI355X — round 10 (resubmit; R6 bench was an
// infra failure "MI355X container failed twice", no measurement taken).
//
// Numerics (verified R1-R9, absmax <=9.8e-4 = perplexity float rounding):
//  * probs == one_hot(argmax)           -> z_q[n] = emb[idx[n]]
//  * argmax_j softmax((-d+g)/TAU) == argmax_j ( g[n,j] - ||e_j||^2 + 2 z_n.e_j )
//  * LAMB*ortho ~1.5e-9 sub-ULP of loss -> skipped (exact no-op in fp32)
//  * loss = mse*(1+BETA^2);  fp16 split z.e = zh.eh + (zh.el' + zl'.eh)*2^-11
//
// R10 (kill cross-XCD atomic contention — R9's measured 109us regression):
//  * R9 post-mortem: outfin @2048 blocks = 109.7us at 173 GB/s. Cause:
//    per-block f64 atomicAdd(mse_acc) + atomicAdd(done_cnt) + threadfence,
//    single cachelines ping-ponging across 8 non-coherent XCD L2s; the
//    cnt[1024] histogram atomics (16 lines, 16K cross-XCD RMWs) were
//    already the hidden ~45us in R6-R8's outfin.
//  * Fix: NO global atomics outside gemm's atomicMax. Stream order chains
//    kernels: prep -> gemm -> outstore (wide, pure streaming broadcast of
//    emb[idx]) -> fin (ONE block: LDS histogram + f64 mse reduce + final
//    loss/perplexity; scattered u loads unroll-8 for latency overlap).
//  * outstore grid/loop identical to R9 minus atomics -> clean attribution.
//  * gemm identical to R9 (BK=32 double-buffered pipeline) — finally
//    measurable in top-5 once outfin shrinks.

#define NROWS 16384
#define NE    1024
#define ED    256
#define EPSF  1e-10f
#define INV2048 4.8828125e-4f
#define BM 128
#define BN 64
#define SCW 68    // score-tile stride: b128 scan ~4-way (1.58x) not 32-way

typedef _Float16 half_t;
typedef __attribute__((ext_vector_type(4))) _Float16 half4;
typedef __attribute__((ext_vector_type(8))) _Float16 half8;
typedef __attribute__((ext_vector_type(16))) float floatx16;
typedef unsigned long long u64;

__device__ __forceinline__ void gl_lds16(const void* g, void* l) {
    __builtin_amdgcn_global_load_lds(
        (const __attribute__((address_space(1))) uint32_t*)g,
        (__attribute__((address_space(3))) uint32_t*)l, 16, 0, 0);
}

// pack (value, code) into an orderable u64; ties -> smaller code (np.argmax)
__device__ __forceinline__ u64 packMax(float v, int code) {
    unsigned int b   = __float_as_uint(v);
    unsigned int key = (b & 0x80000000u) ? ~b : (b | 0x80000000u);
    return ((u64)key << 32) | (unsigned int)(NE - 1 - code);
}

// ---------------- prep: fp16-split z/emb, e-norms, z-norms, zero best
__global__ __launch_bounds__(256) void vq_prep(
        const float* __restrict__ z, const float* __restrict__ emb,
        half_t* __restrict__ zh, half_t* __restrict__ zl,
        half_t* __restrict__ eh, half_t* __restrict__ el,
        float* __restrict__ enorm, float* __restrict__ znorm,
        u64* __restrict__ best)
{
    const int gid = blockIdx.x * 256 + threadIdx.x;
    const int ZQ4 = NROWS * ED / 4;                  // 1048576 = 4096 full blocks
    if (gid < ZQ4) {
        const float4 v = ((const float4*)z)[gid];
        const float x[4] = {v.x, v.y, v.z, v.w};
        half4 h, l;
#pragma unroll
        for (int i = 0; i < 4; ++i) {
            const half_t hi = (half_t)x[i];
            h[i] = hi; l[i] = (half_t)((x[i] - (float)hi) * 2048.0f);
        }
        *(half4*)&zh[(size_t)gid * 4] = h;
        *(half4*)&zl[(size_t)gid * 4] = l;
        float s = v.x*v.x + v.y*v.y + v.z*v.z + v.w*v.w;
#pragma unroll
        for (int o = 32; o; o >>= 1) s += __shfl_down(s, o);
        if ((threadIdx.x & 63) == 0) znorm[gid >> 6] = s;   // 64 thr = 1 row
    } else {
        const int eg = gid - ZQ4;                    // 0..65535
        const float4 v = ((const float4*)emb)[eg];
        const float x[4] = {v.x, v.y, v.z, v.w};
        half4 h, l;
#pragma unroll
        for (int i = 0; i < 4; ++i) {
            const half_t hi = (half_t)x[i];
            h[i] = hi; l[i] = (half_t)((x[i] - (float)hi) * 2048.0f);
        }
        *(half4*)&eh[(size_t)eg * 4] = h;
        *(half4*)&el[(size_t)eg * 4] = l;
        float s = v.x*v.x + v.y*v.y + v.z*v.z + v.w*v.w;
#pragma unroll
        for (int o = 32; o; o >>= 1) s += __shfl_down(s, o);
        if ((threadIdx.x & 63) == 0) enorm[eg >> 6] = s;
        if (eg < NROWS) best[eg] = 0ull;
    }
}

// ---------------- MFMA GEMM + gumbel + per-row argmax (identical to R9)
// 1D grid 2048 blocks, XCD-partitioned (FETCH 60->45MB measured R8).
// 256 thr, 128x64 tile, 4 waves 2m x 2n, wave = 2x1 of 32x32x16 f16 MFMA
// x {hi.hi, hi.lo, lo.hi}. BK=32, double-buffered staging, 1 barrier/K-step.
__global__ __launch_bounds__(256, 2) void vq_gemm(
        const half_t* __restrict__ zh, const half_t* __restrict__ zl,
        const half_t* __restrict__ eh, const half_t* __restrict__ el,
        const float* __restrict__ u, const float* __restrict__ enorm,
        u64* __restrict__ best)
{
    // per buffer (halves): Ah 4096 | Al 4096 | Bh 2048 | Bl 2048  = 24KB
    __shared__ __align__(16) char smem[49152];
    half_t* SM = (half_t*)smem;
    float (*Sc)[SCW] = (float(*)[SCW])smem;        // 34816B, overlays buffers
    u64* parr = (u64*)(smem + 34816);              // 2048B

    const int t    = threadIdx.x;
    const int w    = t >> 6;
    const int lane = t & 63;
    const int lrow = lane & 31;
    const int hw   = lane >> 5;

    const int bid = blockIdx.x;
    const int xcd = bid & 7, c = bid >> 3;
    const int m0 = (xcd * 16 + (c >> 4)) * BM;     // XCD-private m-range
    const int n0 = (c & 15) * BN;
    const int wm = (w >> 1) * 64, wn = (w & 1) * 32;

    // staging descriptors (k-tile-invariant). LDS slot s (16B) holds
    // (row = s>>2, chunk = (s&3)^((row>>1)&3)); pre-swizzled global source,
    // linear LDS dest. 8-quad spread: byte%128 = 64*(row&1)+16*chunk.
    size_t gaoff[2]; size_t gboff;
#pragma unroll
    for (int it = 0; it < 2; ++it) {
        const int s = it * 256 + t;
        const int row = s >> 2;                    // 0..127
        const int cc = (s & 3) ^ ((row >> 1) & 3);
        gaoff[it] = (size_t)(m0 + row) * ED + cc * 8;
    }
    {
        const int row = t >> 2;                    // 0..63
        const int cc = (t & 3) ^ ((row >> 1) & 3);
        gboff = (size_t)(n0 + row) * ED + cc * 8;
    }

    auto STAGE = [&](int kt, int b) {              // k-tile kt -> buffer b
        half_t* base = SM + b * 12288;
        const int kh = kt * 32;
#pragma unroll
        for (int it = 0; it < 2; ++it) {
            const int ldso = (it * 256 + w * 64) * 8;   // wave-uniform base
            gl_lds16(zh + gaoff[it] + kh, base + ldso);
            gl_lds16(zl + gaoff[it] + kh, base + 4096 + ldso);
        }
        gl_lds16(eh + gboff + kh, base + 8192  + w * 64 * 8);
        gl_lds16(el + gboff + kh, base + 10240 + w * 64 * 8);
    };

    floatx16 accH[2] = {};
    floatx16 accX[2] = {};
    const int   col0 = n0 + wn + lrow;
    const float en0  = enorm[col0];
    float ur[2][16];

    STAGE(0, 0);
    __syncthreads();                               // drain stage(0) (one-time)

#pragma unroll
    for (int kt = 0; kt < 8; ++kt) {
        const int cb = kt & 1;
        if (kt + 1 < 8) STAGE(kt + 1, cb ^ 1);     // issue-early: hides under compute
        if (kt == 0) {                             // issue u loads; wait pinned later
            const float* ub = u + (size_t)(m0 + wm + (hw << 2)) * NE + col0;
#pragma unroll
            for (int i = 0; i < 2; ++i)
#pragma unroll
                for (int r = 0; r < 16; ++r)
                    ur[i][r] = ub[(size_t)(i * 32 + (r & 3) + ((r >> 2) << 3)) * NE];
        }
        {   // compute buffer cb
            half_t* base = SM + cb * 12288;
#pragma unroll
            for (int ks = 0; ks < 2; ++ks) {
                const int cch = ks * 2 + hw;       // 16B k-chunk index 0..3
                const int br = wn + lrow;
                const int sb = br * 4 + (cch ^ ((br >> 1) & 3));
                const half8 bh = *(const half8*)&base[8192  + sb * 8];
                const half8 bl = *(const half8*)&base[10240 + sb * 8];
                half8 ah[2], al[2];
#pragma unroll
                for (int i = 0; i < 2; ++i) {
                    const int ar = wm + i * 32 + lrow;
                    const int sa = ar * 4 + (cch ^ ((ar >> 1) & 3));
                    ah[i] = *(const half8*)&base[sa * 8];
                    al[i] = *(const half8*)&base[4096 + sa * 8];
                }
#pragma unroll
                for (int i = 0; i < 2; ++i) {
                    accH[i] = __builtin_amdgcn_mfma_f32_32x32x16_f16(ah[i], bh, accH[i], 0, 0, 0);
                    accX[i] = __builtin_amdgcn_mfma_f32_32x32x16_f16(ah[i], bl, accX[i], 0, 0, 0);
                    accX[i] = __builtin_amdgcn_mfma_f32_32x32x16_f16(al[i], bh, accX[i], 0, 0, 0);
                }
            }
        }
        if (kt == 0) {                             // pin ur live here (rule #17):
#pragma unroll                                     // wait hides under iters 1-7
            for (int i = 0; i < 2; ++i)
#pragma unroll
                for (int r = 0; r < 16; ++r)
                    asm volatile("" :: "v"(ur[i][r]));
        }
        __syncthreads();                           // drains stage(kt+1); buf flip safe
    }
    // loop ends with barrier: all LDS reads done -> Sc overlay safe

    // phase 1: scores (incl. gumbel from pinned regs) -> Sc[row][localcol]
    // C/D layout: col=lane&31, row=(r&3)+8*(r>>2)+4*hw
#pragma unroll
    for (int i = 0; i < 2; ++i) {
#pragma unroll
        for (int r = 0; r < 16; ++r) {
            const int lr = wm + i * 32 + (r & 3) + ((r >> 2) << 3) + (hw << 2);
            const float d = accH[i][r] + accX[i][r] * INV2048;
            const float g = -__logf(-__logf(ur[i][r] + EPSF) + EPSF);
            Sc[lr][wn + lrow] = 2.f * d - en0 + g;
        }
    }
    __syncthreads();

    // phase 2: 2 threads/row scan 32 cols each in registers (ascending cols,
    // strict > keeps first-max = np.argmax tie rule via packMax)
    {
        const int row = t >> 1;
        const int ch  = (t & 1) << 5;
        float bv = -1e38f; int bc = 0;
#pragma unroll
        for (int q = 0; q < 8; ++q) {
            const float4 v = *(const float4*)&Sc[row][ch + (q << 2)];
            const int cc = n0 + ch + (q << 2);
            if (v.x > bv) { bv = v.x; bc = cc; }
            if (v.y > bv) { bv = v.y; bc = cc + 1; }
            if (v.z > bv) { bv = v.z; bc = cc + 2; }
            if (v.w > bv) { bv = v.w; bc = cc + 3; }
        }
        parr[t] = packMax(bv, bc);
    }
    __syncthreads();
    if (t < 128) {
        const u64 a = parr[t << 1], b = parr[(t << 1) + 1];
        atomicMax(&best[m0 + t], a > b ? a : b);
    }
}

// ---------------- outstore: broadcast emb[idx] as z_q_st. Pure streaming,
// ZERO atomics (R9's 109us regression was cross-XCD atomic contention).
// Grid/loop identical to R9's outfin otherwise.
__global__ __launch_bounds__(256) void vq_outstore(
        const float* __restrict__ emb, const u64* __restrict__ best,
        float* __restrict__ out)
{
    __shared__ int ridx[8];
    const int t  = threadIdx.x;
    const int m0 = blockIdx.x * 8;

    if (t < 8)
        ridx[t] = NE - 1 - (int)(best[m0 + t] & 0xFFFFFFFFu);
    __syncthreads();

    // z_q_st == emb[idx] to <=4e-7 of ref's z + (z_q - z). 1KB coalesced
    // store per row; emb row is L2/L3-hot (1MB table).
#pragma unroll
    for (int rr = 0; rr < 8; ++rr) {
        const int j = ridx[rr];
        out[1 + (size_t)(m0 + rr) * ED + t] = emb[(size_t)j * ED + t];
    }
}

// ---------------- fin: ONE block. LDS histogram + f64 mse + loss/perp.
// best/znorm coalesced; u scatter unroll-8 (8 loads in flight / thread).
__global__ __launch_bounds__(256) void vq_fin(
        const u64* __restrict__ best, const float* __restrict__ znorm,
        const float* __restrict__ u, float* __restrict__ out)
{
    __shared__ int    hist[NE];     // 4KB
    __shared__ double redl[4], redp[4];
    const int t = threadIdx.x;

    for (int i = t; i < NE; i += 256) hist[i] = 0;
    __syncthreads();

    double lsum = 0.0;
#pragma unroll 8
    for (int r = t; r < NROWS; r += 256) {
        const u64 p = best[r];
        const unsigned int key = (unsigned int)(p >> 32);
        const int code = NE - 1 - (int)(p & 0xFFFFFFFFu);
        atomicAdd(&hist[code], 1);                 // LDS atomic: block-local
        // invert packMax key -> winning score s = 2 z.e - ||e||^2 + g (bit-exact)
        const unsigned int b = (key & 0x80000000u) ? (key ^ 0x80000000u) : ~key;
        const float s  = __uint_as_float(b);
        const float uv = u[(size_t)r * NE + code];
        const float g  = -__logf(-__logf(uv + EPSF) + EPSF);
        // mse_row = ||z||^2 + ||e||^2 - 2 z.e = znorm - s + g
        lsum += (double)(znorm[r] - s + g);
    }
    __syncthreads();

    double psum = 0.0;
    for (int i = t; i < NE; i += 256) {
        const float em = (float)hist[i] / (float)NROWS;
        psum += (double)(em * logf(em + EPSF));
    }

#pragma unroll
    for (int o = 32; o; o >>= 1) { lsum += __shfl_down(lsum, o); psum += __shfl_down(psum, o); }
    if ((t & 63) == 0) { redl[t >> 6] = lsum; redp[t >> 6] = psum; }
    __syncthreads();
    if (t == 0) {
        const double mse = (redl[0] + redl[1] + redl[2] + redl[3])
                           / (double)((size_t)NROWS * ED);
        const double tot = redp[0] + redp[1] + redp[2] + redp[3];
        out[0] = (float)(mse * 1.0625);   // mse*(1+BETA^2); ortho sub-ULP
        out[1 + (size_t)NROWS * ED] = (float)exp(-tot);
    }
}

extern "C" void kernel_launch(void* const* d_in, const int* in_sizes, int n_in,
                              void* d_out, int out_size, void* d_ws, size_t ws_size,
                              hipStream_t stream) {
    const float* z   = (const float*)d_in[0];
    const float* emb = (const float*)d_in[1];
    const float* u   = (const float*)d_in[2];
    float* out = (float*)d_out;

    float*  enorm    = (float*)((char*)d_ws + 5120);
    u64*    best     = (u64*)((char*)d_ws + 9216);    // 128KB -> ends 140288
    float*  znorm    = (float*)((char*)d_ws + 140288); // 64KB -> ends 205824
    const size_t small_end = 205824;                   // 256-aligned

    const size_t zsplit = (size_t)NROWS * ED * 2;      // 8 MB each
    const size_t esplit = (size_t)NE * ED * 2;         // 0.5 MB each
    const bool bigws = ws_size >= small_end + 2 * zsplit + 2 * esplit;

    half_t *zh, *zl, *eh, *el;
    if (bigws) {
        char* big = (char*)d_ws + small_end;
        zh = (half_t*)big;
        zl = (half_t*)(big + zsplit);
        eh = (half_t*)(big + 2 * zsplit);
        el = (half_t*)(big + 2 * zsplit + esplit);
    } else {
        // stash zh/zl in d_out's z_q_st region (fully consumed by vq_gemm
        // before vq_outstore overwrites it); eh/el in small ws region.
        zh = (half_t*)((char*)d_out + 8);
        zl = (half_t*)((char*)d_out + 8 + zsplit);
        eh = (half_t*)((char*)d_ws + small_end);
        el = (half_t*)((char*)d_ws + small_end + esplit);
    }

    vq_prep<<<(NROWS * ED / 4 + NE * ED / 4) / 256, 256, 0, stream>>>(
        z, emb, zh, zl, eh, el, enorm, znorm, best);
    vq_gemm<<<(NROWS / BM) * (NE / BN), 256, 0, stream>>>(
        zh, zl, eh, el, u, enorm, best);
    vq_outstore<<<NROWS / 8, 256, 0, stream>>>(emb, best, out);
    vq_fin<<<1, 256, 0, stream>>>(best, znorm, u, out);
}

// Round 8
// 185.627 us; speedup vs baseline: 1.3873x; 1.0044x over previous
//
#include <hip/hip_runtime.h>
#include <math.h>
#include <stdint.h>

// VectorQuantizer forward on MI355X — round 11.
//
// Numerics (verified R1-R10, absmax <=9.8e-4 = perplexity float rounding):
//  * probs == one_hot(argmax)           -> z_q[n] = emb[idx[n]]
//  * argmax_j softmax((-d+g)/TAU) == argmax_j ( g[n,j] - ||e_j||^2 + 2 z_n.e_j )
//  * LAMB*ortho ~1.5e-9 sub-ULP of loss -> skipped (exact no-op in fp32)
//  * loss = mse*(1+BETA^2);  fp16 split z.e = zh.eh + (zh.el' + zl'.eh)*2^-11
//
// R11 (occupancy quantum — the never-pulled lever):
//  * R10 post-mortem: EVERY K-loop schedule lands at 55+-2.5us, MfmaUtil 18%,
//    occupancy 24%. Issue math: ~2000cy/wave of work vs ~7us/block measured
//    => 4x off floor, pure un-hidden latency at 2 waves/SIMD (84 VGPR +
//    64 AGPR = 148 -> 256-reg quantum). Scheduling can't fix missing waves.
//  * Fix: 64x64 block tile, wave-tile 32x32 -> acc 32 AGPR; launch_bounds
//    (256,4) caps combined regs at 128 -> 4 waves/SIMD, 4 blocks/CU
//    (LDS 32KB: BK=64 single-buffer R6 skeleton — the best-measured one).
//    Grid 4096, XCD-partitioned: per-XCD set A 2MB + B 1MB = L2-resident.
//  * u loads inline in the score phase (R6 form, best measured).
//  * vq_fin merged into vq_outstore as extra block (both depend only on
//    gemm; one fewer launch).

#define NROWS 16384
#define NE    1024
#define ED    256
#define EPSF  1e-10f
#define INV2048 4.8828125e-4f
#define BM 64
#define BN 64
#define SCW 68    // score-tile stride: b128 scan ~4-way (1.58x) not 32-way

typedef _Float16 half_t;
typedef __attribute__((ext_vector_type(4))) _Float16 half4;
typedef __attribute__((ext_vector_type(8))) _Float16 half8;
typedef __attribute__((ext_vector_type(16))) float floatx16;
typedef unsigned long long u64;

__device__ __forceinline__ void gl_lds16(const void* g, void* l) {
    __builtin_amdgcn_global_load_lds(
        (const __attribute__((address_space(1))) uint32_t*)g,
        (__attribute__((address_space(3))) uint32_t*)l, 16, 0, 0);
}

// pack (value, code) into an orderable u64; ties -> smaller code (np.argmax)
__device__ __forceinline__ u64 packMax(float v, int code) {
    unsigned int b   = __float_as_uint(v);
    unsigned int key = (b & 0x80000000u) ? ~b : (b | 0x80000000u);
    return ((u64)key << 32) | (unsigned int)(NE - 1 - code);
}

// ---------------- prep: fp16-split z/emb, e-norms, z-norms, zero best
__global__ __launch_bounds__(256) void vq_prep(
        const float* __restrict__ z, const float* __restrict__ emb,
        half_t* __restrict__ zh, half_t* __restrict__ zl,
        half_t* __restrict__ eh, half_t* __restrict__ el,
        float* __restrict__ enorm, float* __restrict__ znorm,
        u64* __restrict__ best)
{
    const int gid = blockIdx.x * 256 + threadIdx.x;
    const int ZQ4 = NROWS * ED / 4;                  // 1048576 = 4096 full blocks
    if (gid < ZQ4) {
        const float4 v = ((const float4*)z)[gid];
        const float x[4] = {v.x, v.y, v.z, v.w};
        half4 h, l;
#pragma unroll
        for (int i = 0; i < 4; ++i) {
            const half_t hi = (half_t)x[i];
            h[i] = hi; l[i] = (half_t)((x[i] - (float)hi) * 2048.0f);
        }
        *(half4*)&zh[(size_t)gid * 4] = h;
        *(half4*)&zl[(size_t)gid * 4] = l;
        float s = v.x*v.x + v.y*v.y + v.z*v.z + v.w*v.w;
#pragma unroll
        for (int o = 32; o; o >>= 1) s += __shfl_down(s, o);
        if ((threadIdx.x & 63) == 0) znorm[gid >> 6] = s;   // 64 thr = 1 row
    } else {
        const int eg = gid - ZQ4;                    // 0..65535
        const float4 v = ((const float4*)emb)[eg];
        const float x[4] = {v.x, v.y, v.z, v.w};
        half4 h, l;
#pragma unroll
        for (int i = 0; i < 4; ++i) {
            const half_t hi = (half_t)x[i];
            h[i] = hi; l[i] = (half_t)((x[i] - (float)hi) * 2048.0f);
        }
        *(half4*)&eh[(size_t)eg * 4] = h;
        *(half4*)&el[(size_t)eg * 4] = l;
        float s = v.x*v.x + v.y*v.y + v.z*v.z + v.w*v.w;
#pragma unroll
        for (int o = 32; o; o >>= 1) s += __shfl_down(s, o);
        if ((threadIdx.x & 63) == 0) enorm[eg >> 6] = s;
        if (eg < NROWS) best[eg] = 0ull;
    }
}

// ---------------- MFMA GEMM + gumbel + per-row argmax
// 4096 blocks 1D, XCD-partitioned: xcd=bid&7 owns m-tiles xcd*32..+31; the
// 16 n-tiles of each m-tile run consecutively on that XCD (A,B L2-resident;
// best[] atomics XCD-local). 256 thr = 4 waves, block tile 64x64, wave-tile
// 32x32 (acc 32 AGPR), x {hi.hi, hi.lo, lo.hi} split MFMA. BK=64 single
// buffer, stage-late (R6 skeleton). launch_bounds(256,4) => 4 waves/SIMD.
__global__ __launch_bounds__(256, 4) void vq_gemm(
        const half_t* __restrict__ zh, const half_t* __restrict__ zl,
        const half_t* __restrict__ eh, const half_t* __restrict__ el,
        const float* __restrict__ u, const float* __restrict__ enorm,
        u64* __restrict__ best)
{
    // Ah 8K | Al 8K | Bh 8K | Bl 8K = 32KB; Sc[64][68] (17408B) + parr (2KB)
    // overlay after the K-loop's final barrier.
    __shared__ __align__(16) char smem[32768];
    half_t* Ah = (half_t*)smem;
    half_t* Al = (half_t*)(smem + 8192);
    half_t* Bh = (half_t*)(smem + 16384);
    half_t* Bl = (half_t*)(smem + 24576);
    float (*Sc)[SCW] = (float(*)[SCW])smem;
    u64* parr = (u64*)(smem + 17408);

    const int t    = threadIdx.x;
    const int w    = t >> 6;
    const int lane = t & 63;
    const int lrow = lane & 31;
    const int hw   = lane >> 5;

    const int bid = blockIdx.x;
    const int xcd = bid & 7, c = bid >> 3;          // c: 0..511
    const int m0 = (xcd * 32 + (c >> 4)) * BM;      // XCD-private m-range
    const int n0 = (c & 15) * BN;
    const int wm = (w >> 1) * 32, wn = (w & 1) * 32;

    // staging descriptors. LDS slot s (16B) holds (row = s>>3,
    // chunk = (s&7)^(row&7)) — pre-swizzled global source, linear LDS dest.
    // 512 slots per quarter-buffer, 2 per thread.
    size_t gaoff[2], gboff[2];
#pragma unroll
    for (int it = 0; it < 2; ++it) {
        const int s = it * 256 + t;
        const int row = s >> 3;                     // 0..63
        const int cc = (s & 7) ^ (row & 7);
        gaoff[it] = (size_t)(m0 + row) * ED + cc * 8;
        gboff[it] = (size_t)(n0 + row) * ED + cc * 8;
    }

    auto STAGE = [&](int kc) {
#pragma unroll
        for (int it = 0; it < 2; ++it) {
            const int ldso = (it * 256 + w * 64) * 8;   // wave-uniform base
            gl_lds16(zh + gaoff[it] + kc, Ah + ldso);
            gl_lds16(zl + gaoff[it] + kc, Al + ldso);
            gl_lds16(eh + gboff[it] + kc, Bh + ldso);
            gl_lds16(el + gboff[it] + kc, Bl + ldso);
        }
    };

    floatx16 accH = {};
    floatx16 accX = {};

    STAGE(0);
    for (int kc = 0; kc < ED; kc += 64) {
        __syncthreads();                            // drains stage(kc)
#pragma unroll
        for (int ks = 0; ks < 4; ++ks) {
            const int cch = ks * 2 + hw;            // 16B k-chunk index 0..7
            const int ar = wm + lrow;
            const int br = wn + lrow;
            const int sa = ar * 8 + (cch ^ (ar & 7));
            const int sb = br * 8 + (cch ^ (br & 7));
            const half8 ah = *(const half8*)&Ah[sa * 8];
            const half8 al = *(const half8*)&Al[sa * 8];
            const half8 bh = *(const half8*)&Bh[sb * 8];
            const half8 bl = *(const half8*)&Bl[sb * 8];
            accH = __builtin_amdgcn_mfma_f32_32x32x16_f16(ah, bh, accH, 0, 0, 0);
            accX = __builtin_amdgcn_mfma_f32_32x32x16_f16(ah, bl, accX, 0, 0, 0);
            accX = __builtin_amdgcn_mfma_f32_32x32x16_f16(al, bh, accX, 0, 0, 0);
        }
        __syncthreads();                            // all LDS reads of tile done
        if (kc + 64 < ED) STAGE(kc + 64);
    }
    // loop ends with barrier: staging LDS dead -> Sc overlay safe

    // phase 1: scores (incl. gumbel, u inline) -> Sc[row][localcol]
    // C/D layout: col=lane&31, row=(r&3)+8*(r>>2)+4*hw
    const int   col0 = n0 + wn + lrow;
    const float en0  = enorm[col0];
#pragma unroll
    for (int r = 0; r < 16; ++r) {
        const int lr = wm + (r & 3) + ((r >> 2) << 3) + (hw << 2);
        const float d  = accH[r] + accX[r] * INV2048;
        const float uv = u[(size_t)(m0 + lr) * NE + col0];
        const float g  = -__logf(-__logf(uv + EPSF) + EPSF);
        Sc[lr][wn + lrow] = 2.f * d - en0 + g;
    }
    __syncthreads();

    // phase 2: 4 threads/row scan 16 cols each in registers (ascending cols,
    // strict > keeps first-max = np.argmax tie rule via packMax)
    {
        const int row = t >> 2;
        const int ch  = (t & 3) << 4;
        float bv = -1e38f; int bc = 0;
#pragma unroll
        for (int q = 0; q < 4; ++q) {
            const float4 v = *(const float4*)&Sc[row][ch + (q << 2)];
            const int cc = n0 + ch + (q << 2);
            if (v.x > bv) { bv = v.x; bc = cc; }
            if (v.y > bv) { bv = v.y; bc = cc + 1; }
            if (v.z > bv) { bv = v.z; bc = cc + 2; }
            if (v.w > bv) { bv = v.w; bc = cc + 3; }
        }
        parr[t] = packMax(bv, bc);
    }
    __syncthreads();
    if (t < 64) {
        const u64 a = parr[(t << 2)],     b = parr[(t << 2) + 1];
        const u64 e = parr[(t << 2) + 2], f = parr[(t << 2) + 3];
        const u64 m1 = a > b ? a : b;
        const u64 m2 = e > f ? e : f;
        atomicMax(&best[m0 + t], m1 > m2 ? m1 : m2);
    }
}

// ---------------- outstore: broadcast emb[idx] as z_q_st (pure streaming,
// zero global atomics). Block NROWS/8 (the +1 block) runs the finalizer:
// LDS histogram + f64 mse from the packed scores + loss/perplexity.
__global__ __launch_bounds__(256) void vq_outstore(
        const float* __restrict__ emb, const u64* __restrict__ best,
        const float* __restrict__ znorm, const float* __restrict__ u,
        float* __restrict__ out)
{
    const int t = threadIdx.x;

    if (blockIdx.x == NROWS / 8) {
        // ---- finalizer block (depends only on gemm's best[], like outstore)
        __shared__ int    hist[NE];     // 4KB
        __shared__ double redl[4], redp[4];
        for (int i = t; i < NE; i += 256) hist[i] = 0;
        __syncthreads();

        double lsum = 0.0;
#pragma unroll 8
        for (int r = t; r < NROWS; r += 256) {
            const u64 p = best[r];
            const unsigned int key = (unsigned int)(p >> 32);
            const int code = NE - 1 - (int)(p & 0xFFFFFFFFu);
            atomicAdd(&hist[code], 1);             // LDS atomic: block-local
            // invert packMax key -> winning score s = 2 z.e - ||e||^2 + g
            const unsigned int b = (key & 0x80000000u) ? (key ^ 0x80000000u) : ~key;
            const float s  = __uint_as_float(b);
            const float uv = u[(size_t)r * NE + code];
            const float g  = -__logf(-__logf(uv + EPSF) + EPSF);
            // mse_row = ||z||^2 + ||e||^2 - 2 z.e = znorm - s + g
            lsum += (double)(znorm[r] - s + g);
        }
        __syncthreads();

        double psum = 0.0;
        for (int i = t; i < NE; i += 256) {
            const float em = (float)hist[i] / (float)NROWS;
            psum += (double)(em * logf(em + EPSF));
        }
#pragma unroll
        for (int o = 32; o; o >>= 1) { lsum += __shfl_down(lsum, o); psum += __shfl_down(psum, o); }
        if ((t & 63) == 0) { redl[t >> 6] = lsum; redp[t >> 6] = psum; }
        __syncthreads();
        if (t == 0) {
            const double mse = (redl[0] + redl[1] + redl[2] + redl[3])
                               / (double)((size_t)NROWS * ED);
            const double tot = redp[0] + redp[1] + redp[2] + redp[3];
            out[0] = (float)(mse * 1.0625);   // mse*(1+BETA^2); ortho sub-ULP
            out[1 + (size_t)NROWS * ED] = (float)exp(-tot);
        }
        return;
    }

    __shared__ int ridx[8];
    const int m0 = blockIdx.x * 8;
    if (t < 8)
        ridx[t] = NE - 1 - (int)(best[m0 + t] & 0xFFFFFFFFu);
    __syncthreads();

    // z_q_st == emb[idx] to <=4e-7 of ref's z + (z_q - z). 1KB coalesced
    // store per row; emb row is L2/L3-hot (1MB table).
#pragma unroll
    for (int rr = 0; rr < 8; ++rr) {
        const int j = ridx[rr];
        out[1 + (size_t)(m0 + rr) * ED + t] = emb[(size_t)j * ED + t];
    }
}

extern "C" void kernel_launch(void* const* d_in, const int* in_sizes, int n_in,
                              void* d_out, int out_size, void* d_ws, size_t ws_size,
                              hipStream_t stream) {
    const float* z   = (const float*)d_in[0];
    const float* emb = (const float*)d_in[1];
    const float* u   = (const float*)d_in[2];
    float* out = (float*)d_out;

    float*  enorm    = (float*)((char*)d_ws + 5120);
    u64*    best     = (u64*)((char*)d_ws + 9216);    // 128KB -> ends 140288
    float*  znorm    = (float*)((char*)d_ws + 140288); // 64KB -> ends 205824
    const size_t small_end = 205824;                   // 256-aligned

    const size_t zsplit = (size_t)NROWS * ED * 2;      // 8 MB each
    const size_t esplit = (size_t)NE * ED * 2;         // 0.5 MB each
    const bool bigws = ws_size >= small_end + 2 * zsplit + 2 * esplit;

    half_t *zh, *zl, *eh, *el;
    if (bigws) {
        char* big = (char*)d_ws + small_end;
        zh = (half_t*)big;
        zl = (half_t*)(big + zsplit);
        eh = (half_t*)(big + 2 * zsplit);
        el = (half_t*)(big + 2 * zsplit + esplit);
    } else {
        // stash zh/zl in d_out's z_q_st region (fully consumed by vq_gemm
        // before vq_outstore overwrites it); eh/el in small ws region.
        zh = (half_t*)((char*)d_out + 8);
        zl = (half_t*)((char*)d_out + 8 + zsplit);
        eh = (half_t*)((char*)d_ws + small_end);
        el = (half_t*)((char*)d_ws + small_end + esplit);
    }

    vq_prep<<<(NROWS * ED / 4 + NE * ED / 4) / 256, 256, 0, stream>>>(
        z, emb, zh, zl, eh, el, enorm, znorm, best);
    vq_gemm<<<(NROWS / BM) * (NE / BN), 256, 0, stream>>>(
        zh, zl, eh, el, u, enorm, best);
    vq_outstore<<<NROWS / 8 + 1, 256, 0, stream>>>(emb, best, znorm, u, out);
}

// Round 9
// 174.295 us; speedup vs baseline: 1.4774x; 1.0650x over previous
//
#include <hip/hip_runtime.h>
#include <math.h>
#include <stdint.h>

// VectorQuantizer forward on MI355X — round 12.
//
// Numerics (verified R1-R11, absmax <=9.8e-4 = perplexity float rounding):
//  * probs == one_hot(argmax)           -> z_q[n] = emb[idx[n]]
//  * argmax_j softmax((-d+g)/TAU) == argmax_j ( g[n,j] - ||e_j||^2 + 2 z_n.e_j )
//  * LAMB*ortho ~1.5e-9 sub-ULP of loss -> skipped (exact no-op in fp32)
//  * loss = mse*(1+BETA^2);  fp16 split z.e = zh.eh + (zh.el' + zl'.eh)*2^-11
//
// R12 (tail restructure — gemm byte-identical to R11):
//  * R11 post-mortem: occupancy 24->32% with ZERO time change => gemm's 55us
//    is not coverable-latency-bound; it is invariant across 5 schedules.
//    Meanwhile total-gemm ~= 130us never appeared in top-5: three kernels
//    <55us each. Latency math fingers vq_fin: ONE block doing 16K scattered
//    4B u loads => ~128 in flight on one CU x ~900cy => ~45-50us serialized.
//    R10 moved the cross-XCD-atomic cost into a single-CU latency trap.
//  * Fix: outstore (2048-wide) recomputes g + mse_row per row, writes
//    partial[bid] (f64 plain store) + idx[row] (exclusive owner) — zero
//    atomics. fin becomes ~80KB of coalesced reads (idx hist via LDS
//    atomics + partial sum) ~3us.
//  * prep: 8 elems/thread (2x float4 in, 2x half8 16B out, width-32 shfl
//    row norms) — strictly fewer instructions at same traffic.

#define NROWS 16384
#define NE    1024
#define ED    256
#define EPSF  1e-10f
#define INV2048 4.8828125e-4f
#define BM 64
#define BN 64
#define SCW 68    // score-tile stride: b128 scan ~4-way (1.58x) not 32-way

typedef _Float16 half_t;
typedef __attribute__((ext_vector_type(4))) _Float16 half4;
typedef __attribute__((ext_vector_type(8))) _Float16 half8;
typedef __attribute__((ext_vector_type(16))) float floatx16;
typedef unsigned long long u64;

__device__ __forceinline__ void gl_lds16(const void* g, void* l) {
    __builtin_amdgcn_global_load_lds(
        (const __attribute__((address_space(1))) uint32_t*)g,
        (__attribute__((address_space(3))) uint32_t*)l, 16, 0, 0);
}

// pack (value, code) into an orderable u64; ties -> smaller code (np.argmax)
__device__ __forceinline__ u64 packMax(float v, int code) {
    unsigned int b   = __float_as_uint(v);
    unsigned int key = (b & 0x80000000u) ? ~b : (b | 0x80000000u);
    return ((u64)key << 32) | (unsigned int)(NE - 1 - code);
}

// ---------------- prep: fp16-split z/emb, e-norms, z-norms, zero best.
// 8 elems/thread: 2x float4 loads, 2x 16B half8 stores, width-32 shfl norms.
__global__ __launch_bounds__(256) void vq_prep(
        const float* __restrict__ z, const float* __restrict__ emb,
        half_t* __restrict__ zh, half_t* __restrict__ zl,
        half_t* __restrict__ eh, half_t* __restrict__ el,
        float* __restrict__ enorm, float* __restrict__ znorm,
        u64* __restrict__ best)
{
    const int gid = blockIdx.x * 256 + threadIdx.x;
    const int ZQ8 = NROWS * ED / 8;                  // 524288 = 2048 full blocks
    if (gid < ZQ8) {
        const float4 v0 = ((const float4*)z)[(size_t)gid * 2];
        const float4 v1 = ((const float4*)z)[(size_t)gid * 2 + 1];
        const float x[8] = {v0.x, v0.y, v0.z, v0.w, v1.x, v1.y, v1.z, v1.w};
        half8 h, l;
        float s = 0.f;
#pragma unroll
        for (int i = 0; i < 8; ++i) {
            const half_t hi = (half_t)x[i];
            h[i] = hi; l[i] = (half_t)((x[i] - (float)hi) * 2048.0f);
            s = fmaf(x[i], x[i], s);
        }
        *(half8*)&zh[(size_t)gid * 8] = h;
        *(half8*)&zl[(size_t)gid * 8] = l;
        // 32 threads cover one 256-elem row (wave-aligned: 64|256)
#pragma unroll
        for (int o = 16; o; o >>= 1) s += __shfl_down(s, o, 32);
        if ((threadIdx.x & 31) == 0) znorm[gid >> 5] = s;
    } else {
        const int eg = gid - ZQ8;                    // 0..32767
        const float4 v0 = ((const float4*)emb)[(size_t)eg * 2];
        const float4 v1 = ((const float4*)emb)[(size_t)eg * 2 + 1];
        const float x[8] = {v0.x, v0.y, v0.z, v0.w, v1.x, v1.y, v1.z, v1.w};
        half8 h, l;
        float s = 0.f;
#pragma unroll
        for (int i = 0; i < 8; ++i) {
            const half_t hi = (half_t)x[i];
            h[i] = hi; l[i] = (half_t)((x[i] - (float)hi) * 2048.0f);
            s = fmaf(x[i], x[i], s);
        }
        *(half8*)&eh[(size_t)eg * 8] = h;
        *(half8*)&el[(size_t)eg * 8] = l;
#pragma unroll
        for (int o = 16; o; o >>= 1) s += __shfl_down(s, o, 32);
        if ((threadIdx.x & 31) == 0) enorm[eg >> 5] = s;
        if (eg < NROWS) best[eg] = 0ull;
    }
}

// ---------------- MFMA GEMM + gumbel + per-row argmax (byte-identical R11)
// 4096 blocks 1D, XCD-partitioned. 256 thr = 4 waves, block tile 64x64,
// wave-tile 32x32 (acc 32 AGPR), x {hi.hi, hi.lo, lo.hi} split MFMA.
// BK=64 single buffer, stage-late. launch_bounds(256,4).
__global__ __launch_bounds__(256, 4) void vq_gemm(
        const half_t* __restrict__ zh, const half_t* __restrict__ zl,
        const half_t* __restrict__ eh, const half_t* __restrict__ el,
        const float* __restrict__ u, const float* __restrict__ enorm,
        u64* __restrict__ best)
{
    // Ah 8K | Al 8K | Bh 8K | Bl 8K = 32KB; Sc[64][68] (17408B) + parr (2KB)
    // overlay after the K-loop's final barrier.
    __shared__ __align__(16) char smem[32768];
    half_t* Ah = (half_t*)smem;
    half_t* Al = (half_t*)(smem + 8192);
    half_t* Bh = (half_t*)(smem + 16384);
    half_t* Bl = (half_t*)(smem + 24576);
    float (*Sc)[SCW] = (float(*)[SCW])smem;
    u64* parr = (u64*)(smem + 17408);

    const int t    = threadIdx.x;
    const int w    = t >> 6;
    const int lane = t & 63;
    const int lrow = lane & 31;
    const int hw   = lane >> 5;

    const int bid = blockIdx.x;
    const int xcd = bid & 7, c = bid >> 3;          // c: 0..511
    const int m0 = (xcd * 32 + (c >> 4)) * BM;      // XCD-private m-range
    const int n0 = (c & 15) * BN;
    const int wm = (w >> 1) * 32, wn = (w & 1) * 32;

    // staging descriptors. LDS slot s (16B) holds (row = s>>3,
    // chunk = (s&7)^(row&7)) — pre-swizzled global source, linear LDS dest.
    size_t gaoff[2], gboff[2];
#pragma unroll
    for (int it = 0; it < 2; ++it) {
        const int s = it * 256 + t;
        const int row = s >> 3;                     // 0..63
        const int cc = (s & 7) ^ (row & 7);
        gaoff[it] = (size_t)(m0 + row) * ED + cc * 8;
        gboff[it] = (size_t)(n0 + row) * ED + cc * 8;
    }

    auto STAGE = [&](int kc) {
#pragma unroll
        for (int it = 0; it < 2; ++it) {
            const int ldso = (it * 256 + w * 64) * 8;   // wave-uniform base
            gl_lds16(zh + gaoff[it] + kc, Ah + ldso);
            gl_lds16(zl + gaoff[it] + kc, Al + ldso);
            gl_lds16(eh + gboff[it] + kc, Bh + ldso);
            gl_lds16(el + gboff[it] + kc, Bl + ldso);
        }
    };

    floatx16 accH = {};
    floatx16 accX = {};

    STAGE(0);
    for (int kc = 0; kc < ED; kc += 64) {
        __syncthreads();                            // drains stage(kc)
#pragma unroll
        for (int ks = 0; ks < 4; ++ks) {
            const int cch = ks * 2 + hw;            // 16B k-chunk index 0..7
            const int ar = wm + lrow;
            const int br = wn + lrow;
            const int sa = ar * 8 + (cch ^ (ar & 7));
            const int sb = br * 8 + (cch ^ (br & 7));
            const half8 ah = *(const half8*)&Ah[sa * 8];
            const half8 al = *(const half8*)&Al[sa * 8];
            const half8 bh = *(const half8*)&Bh[sb * 8];
            const half8 bl = *(const half8*)&Bl[sb * 8];
            accH = __builtin_amdgcn_mfma_f32_32x32x16_f16(ah, bh, accH, 0, 0, 0);
            accX = __builtin_amdgcn_mfma_f32_32x32x16_f16(ah, bl, accX, 0, 0, 0);
            accX = __builtin_amdgcn_mfma_f32_32x32x16_f16(al, bh, accX, 0, 0, 0);
        }
        __syncthreads();                            // all LDS reads of tile done
        if (kc + 64 < ED) STAGE(kc + 64);
    }
    // loop ends with barrier: staging LDS dead -> Sc overlay safe

    // phase 1: scores (incl. gumbel, u inline) -> Sc[row][localcol]
    // C/D layout: col=lane&31, row=(r&3)+8*(r>>2)+4*hw
    const int   col0 = n0 + wn + lrow;
    const float en0  = enorm[col0];
#pragma unroll
    for (int r = 0; r < 16; ++r) {
        const int lr = wm + (r & 3) + ((r >> 2) << 3) + (hw << 2);
        const float d  = accH[r] + accX[r] * INV2048;
        const float uv = u[(size_t)(m0 + lr) * NE + col0];
        const float g  = -__logf(-__logf(uv + EPSF) + EPSF);
        Sc[lr][wn + lrow] = 2.f * d - en0 + g;
    }
    __syncthreads();

    // phase 2: 4 threads/row scan 16 cols each in registers (ascending cols,
    // strict > keeps first-max = np.argmax tie rule via packMax)
    {
        const int row = t >> 2;
        const int ch  = (t & 3) << 4;
        float bv = -1e38f; int bc = 0;
#pragma unroll
        for (int q = 0; q < 4; ++q) {
            const float4 v = *(const float4*)&Sc[row][ch + (q << 2)];
            const int cc = n0 + ch + (q << 2);
            if (v.x > bv) { bv = v.x; bc = cc; }
            if (v.y > bv) { bv = v.y; bc = cc + 1; }
            if (v.z > bv) { bv = v.z; bc = cc + 2; }
            if (v.w > bv) { bv = v.w; bc = cc + 3; }
        }
        parr[t] = packMax(bv, bc);
    }
    __syncthreads();
    if (t < 64) {
        const u64 a = parr[(t << 2)],     b = parr[(t << 2) + 1];
        const u64 e = parr[(t << 2) + 2], f = parr[(t << 2) + 3];
        const u64 m1 = a > b ? a : b;
        const u64 m2 = e > f ? e : f;
        atomicMax(&best[m0 + t], m1 > m2 ? m1 : m2);
    }
}

// ---------------- outstore: broadcast emb[idx] as z_q_st + per-row mse.
// 2048 blocks x 8 rows, ZERO atomics: idx[row] has an exclusive owner,
// partial[bid] is a plain f64 store. The 8 scattered u loads per block are
// latency-hidden by grid width (the load that serialized R10's 1-block fin).
__global__ __launch_bounds__(256) void vq_outstore(
        const float* __restrict__ emb, const u64* __restrict__ best,
        const float* __restrict__ znorm, const float* __restrict__ u,
        int* __restrict__ idxArr, double* __restrict__ partial,
        float* __restrict__ out)
{
    __shared__ int   ridx[8];
    __shared__ float rmse[8];
    const int t  = threadIdx.x;
    const int m0 = blockIdx.x * 8;

    if (t < 8) {
        const u64 p = best[m0 + t];                    // written pre-launch
        const unsigned int key = (unsigned int)(p >> 32);
        const int code = NE - 1 - (int)(p & 0xFFFFFFFFu);
        ridx[t] = code;
        idxArr[m0 + t] = code;
        // invert packMax key -> winning score s = 2 z.e - ||e||^2 + g (bit-exact)
        const unsigned int b = (key & 0x80000000u) ? (key ^ 0x80000000u) : ~key;
        const float s  = __uint_as_float(b);
        const float uv = u[(size_t)(m0 + t) * NE + code];
        const float g  = -__logf(-__logf(uv + EPSF) + EPSF);
        // mse_row = ||z||^2 + ||e||^2 - 2 z.e = znorm - s + g
        rmse[t] = znorm[m0 + t] - s + g;
    }
    __syncthreads();
    if (t == 0) {
        double acc = 0.0;
#pragma unroll
        for (int r = 0; r < 8; ++r) acc += (double)rmse[r];
        partial[blockIdx.x] = acc;
    }

    // z_q_st == emb[idx] to <=4e-7 of ref's z + (z_q - z). 1KB coalesced
    // store per row; emb row is L2/L3-hot (1MB table).
#pragma unroll
    for (int rr = 0; rr < 8; ++rr) {
        const int j = ridx[rr];
        out[1 + (size_t)(m0 + rr) * ED + t] = emb[(size_t)j * ED + t];
    }
}

// ---------------- fin: ONE block, ~80KB coalesced. LDS histogram from
// idx[], lsum from partial[], write loss + perplexity.
__global__ __launch_bounds__(256) void vq_fin(
        const int* __restrict__ idxArr, const double* __restrict__ partial,
        float* __restrict__ out)
{
    __shared__ int    hist[NE];     // 4KB
    __shared__ double redl[4], redp[4];
    const int t = threadIdx.x;

    for (int i = t; i < NE; i += 256) hist[i] = 0;
    __syncthreads();

    for (int r = t; r < NROWS; r += 256)
        atomicAdd(&hist[idxArr[r]], 1);            // LDS atomic: block-local

    double lsum = 0.0;
    for (int b = t; b < NROWS / 8; b += 256)       // 8 doubles/thread, coalesced
        lsum += partial[b];
    __syncthreads();                               // hist complete

    double psum = 0.0;
    for (int i = t; i < NE; i += 256) {
        const float em = (float)hist[i] / (float)NROWS;
        psum += (double)(em * logf(em + EPSF));
    }

#pragma unroll
    for (int o = 32; o; o >>= 1) { lsum += __shfl_down(lsum, o); psum += __shfl_down(psum, o); }
    if ((t & 63) == 0) { redl[t >> 6] = lsum; redp[t >> 6] = psum; }
    __syncthreads();
    if (t == 0) {
        const double mse = (redl[0] + redl[1] + redl[2] + redl[3])
                           / (double)((size_t)NROWS * ED);
        const double tot = redp[0] + redp[1] + redp[2] + redp[3];
        out[0] = (float)(mse * 1.0625);   // mse*(1+BETA^2); ortho sub-ULP
        out[1 + (size_t)NROWS * ED] = (float)exp(-tot);
    }
}

extern "C" void kernel_launch(void* const* d_in, const int* in_sizes, int n_in,
                              void* d_out, int out_size, void* d_ws, size_t ws_size,
                              hipStream_t stream) {
    const float* z   = (const float*)d_in[0];
    const float* emb = (const float*)d_in[1];
    const float* u   = (const float*)d_in[2];
    float* out = (float*)d_out;

    float*  enorm    = (float*)((char*)d_ws + 5120);
    u64*    best     = (u64*)((char*)d_ws + 9216);     // 128KB -> ends 140288
    float*  znorm    = (float*)((char*)d_ws + 140288); // 64KB  -> ends 205824
    int*    idxArr   = (int*)((char*)d_ws + 205824);   // 64KB  -> ends 271360
    double* partial  = (double*)((char*)d_ws + 271360);// 16KB  -> ends 287744
    const size_t small_end = 287744;                   // 256-aligned

    const size_t zsplit = (size_t)NROWS * ED * 2;      // 8 MB each
    const size_t esplit = (size_t)NE * ED * 2;         // 0.5 MB each
    const bool bigws = ws_size >= small_end + 2 * zsplit + 2 * esplit;

    half_t *zh, *zl, *eh, *el;
    if (bigws) {
        char* big = (char*)d_ws + small_end;
        zh = (half_t*)big;
        zl = (half_t*)(big + zsplit);
        eh = (half_t*)(big + 2 * zsplit);
        el = (half_t*)(big + 2 * zsplit + esplit);
    } else {
        // stash zh/zl in d_out's z_q_st region (fully consumed by vq_gemm
        // before vq_outstore overwrites it); eh/el in small ws region.
        zh = (half_t*)((char*)d_out + 8);
        zl = (half_t*)((char*)d_out + 8 + zsplit);
        eh = (half_t*)((char*)d_ws + small_end);
        el = (half_t*)((char*)d_ws + small_end + esplit);
    }

    vq_prep<<<(NROWS * ED / 8 + NE * ED / 8) / 256, 256, 0, stream>>>(
        z, emb, zh, zl, eh, el, enorm, znorm, best);
    vq_gemm<<<(NROWS / BM) * (NE / BN), 256, 0, stream>>>(
        zh, zl, eh, el, u, enorm, best);
    vq_outstore<<<NROWS / 8, 256, 0, stream>>>(
        emb, best, znorm, u, idxArr, partial, out);
    vq_fin<<<1, 256, 0, stream>>>(idxArr, partial, out);
}